// Round 2
// baseline (505.257 us; speedup 1.0000x reference)
//
#include <hip/hip_runtime.h>
#include <limits.h>
#include <math.h>

#define WOS_ZERO_TOL 1e-6f

// One wave (64 lanes) per pixel. Lane d (0..53) owns candidate d:
//   d in [0,27):  inp_d = patch value (c = d/9, i = (d%9)/3, j = d%3)
//   d in [27,54): inp_d = -patch value of (d-27); lanes 54..63 idle (-inf).
// Per output channel nc:
//   1) rank_d = #{d' : mx_{d'} > mx_d  or (==, d' < d)}   (stable desc sort rank)
//   2) ds_permute weights into rank order
//   3) sequential 54-step scan (bit-exact np.cumsum order); record own prefix
//   4) select: among nz & acc<=bias the max acc, else among nz the min acc;
//      done with one max-reduction on an integer-monotone composite key.
__global__ __launch_bounds__(256) void wos_kernel(
    const float* __restrict__ x,       // (8,3,64,64)
    const float* __restrict__ mask,    // (16,54)
    const float* __restrict__ weight,  // (16,54)
    const float* __restrict__ bias,    // (16,1)
    float* __restrict__ out)           // flat: [pixel*16 + nc]
{
    const int lane = threadIdx.x & 63;
    const int wid  = threadIdx.x >> 6;
    const int p    = blockIdx.x * 4 + wid;   // pixel in [0, 32768)
    const int b    = p >> 12;
    const int l    = p & 4095;
    const int h    = l >> 6;
    const int w    = l & 63;

    // Gather this lane's patch value (zero padding at borders).
    float inp = 0.0f;
    if (lane < 54) {
        int dm  = (lane < 27) ? lane : lane - 27;
        int c   = dm / 9;
        int rem = dm - 9 * c;
        int di  = rem / 3;
        int dj  = rem - 3 * di;
        int hh  = h + di - 1;
        int ww  = w + dj - 1;
        if (hh >= 0 && hh < 64 && ww >= 0 && ww < 64) {
            float v = x[((b * 3 + c) << 12) + (hh << 6) + ww];
            inp = (lane < 27) ? v : -v;
        }
    }

    float res = 0.0f;
    #pragma unroll 1
    for (int nc = 0; nc < 16; ++nc) {
        float mk   = (lane < 54) ? mask[nc * 54 + lane]   : 0.0f;
        float wv   = (lane < 54) ? weight[nc * 54 + lane] : 0.0f;
        float mxv  = (lane < 54) ? (inp + mk) : -INFINITY;
        float wsel = (wv > WOS_ZERO_TOL) ? wv : 0.0f;

        // 1) stable descending-sort rank (ties broken by lane index).
        //    Real lanes get ranks 0..53; -inf lanes all get 54 (harmless:
        //    their ds_permute pushes collide at an unread slot with wsel=0).
        int rank = 0;
        #pragma unroll
        for (int dp = 0; dp < 54; ++dp) {
            float vp = __int_as_float(__builtin_amdgcn_readlane(__float_as_int(mxv), dp));
            rank += (vp > mxv || (vp == mxv && dp < lane)) ? 1 : 0;
        }

        // 2) route wsel into sorted order: lane r receives weight of rank-r entry.
        float ws_r = __int_as_float(
            __builtin_amdgcn_ds_permute(rank << 2, __float_as_int(wsel)));

        // 3) sequential scan in sorted order — identical f32 association
        //    order to the reference's np.cumsum → bit-exact accw.
        float acc  = 0.0f;
        float cacc = 0.0f;
        #pragma unroll
        for (int r = 0; r < 54; ++r) {
            float wr = __int_as_float(__builtin_amdgcn_readlane(__float_as_int(ws_r), r));
            acc += wr;
            if (rank == r) cacc = acc;
        }

        // 4) selection. cacc > 0 for nz lanes, so its f32 bit pattern is
        //    order-preserving as a signed int. Flagged keys positive (max =
        //    largest acc <= bias); fallback keys negative (max = smallest acc);
        //    inactive INT_MIN.
        const bool  nzf  = wsel > 0.0f;
        const float bv   = bias[nc];
        const bool  flag = nzf && (cacc <= bv);
        int bitsc = __float_as_int(cacc);
        int key   = flag ? bitsc : (nzf ? -bitsc : INT_MIN);
        float val = mxv;
        #pragma unroll
        for (int off = 32; off > 0; off >>= 1) {
            int   ok = __shfl_xor(key, off);
            float ov = __shfl_xor(val, off);
            if (ok > key) { key = ok; val = ov; }
        }
        if (lane == nc) res = val;   // butterfly leaves answer in all lanes
    }

    if (lane < 16) out[p * 16 + lane] = res;
}

extern "C" void kernel_launch(void* const* d_in, const int* in_sizes, int n_in,
                              void* d_out, int out_size, void* d_ws, size_t ws_size,
                              hipStream_t stream) {
    const float* x      = (const float*)d_in[0];
    const float* mask   = (const float*)d_in[1];
    const float* weight = (const float*)d_in[2];
    const float* bias   = (const float*)d_in[3];
    float* out = (float*)d_out;

    // 32768 pixels, 4 waves (pixels) per 256-thread block -> 8192 blocks
    wos_kernel<<<dim3(8192), dim3(256), 0, stream>>>(x, mask, weight, bias, out);
}

// Round 4
// 496.406 us; speedup vs baseline: 1.0178x; 1.0178x over previous
//
#include <hip/hip_runtime.h>
#include <limits.h>
#include <math.h>
#include <stdint.h>

#define WOS_ZERO_TOL 1e-6f

// One wave (64 lanes) per pixel. Phase 1: lane d owns candidate d
//   d in [0,27):  inp_d = patch value (c = d/9, i = (d%9)/3, j = d%3)
//   d in [27,54): inp_d = -patch value of (d-27); lanes 54..63 idle (-inf).
// Per output channel nc:
//   1) 64-bit stable-sort key k = ordered(mx) :: (63-lane); rank = #{k' > k}
//      (strict u64 compare reproduces jnp stable descending argsort exactly)
//   2) ds_permute weight AND mx into sorted coords (lane = sorted position)
//   3) sequential 54-step scan, bit-exact np.cumsum association order;
//      each lane captures the prefix at its own position
//   4) selection is wave-uniform: flag = ballot(acc<=bias) & ballot(nz);
//      pick last flag bit (or first nz bit); one dynamic readlane for answer.
__global__ __launch_bounds__(256) void wos_kernel(
    const float* __restrict__ x,       // (8,3,64,64)
    const float* __restrict__ mask,    // (16,54)
    const float* __restrict__ weight,  // (16,54)
    const float* __restrict__ bias,    // (16,1)
    float* __restrict__ out)           // flat: [pixel*16 + nc]
{
    const int lane = threadIdx.x & 63;
    const int wid  = threadIdx.x >> 6;
    const int p    = blockIdx.x * 4 + wid;   // pixel in [0, 32768)
    const int b    = p >> 12;
    const int l    = p & 4095;
    const int h    = l >> 6;
    const int w    = l & 63;

    // Gather this lane's patch value (zero padding at borders).
    float inp = 0.0f;
    if (lane < 54) {
        int dm  = (lane < 27) ? lane : lane - 27;
        int c   = dm / 9;
        int rem = dm - 9 * c;
        int di  = rem / 3;
        int dj  = rem - 3 * di;
        int hh  = h + di - 1;
        int ww  = w + dj - 1;
        if (hh >= 0 && hh < 64 && ww >= 0 && ww < 64) {
            float v = x[((b * 3 + c) << 12) + (hh << 6) + ww];
            inp = (lane < 27) ? v : -v;
        }
    }

    const uint32_t inv_lane = (uint32_t)(63 - lane);
    float res = 0.0f;

    #pragma unroll 1
    for (int nc = 0; nc < 16; ++nc) {
        float mk   = (lane < 54) ? mask[nc * 54 + lane]   : 0.0f;
        float wv   = (lane < 54) ? weight[nc * 54 + lane] : 0.0f;
        float mxv  = (lane < 54) ? (inp + mk) : -INFINITY;
        float wsel = (wv > WOS_ZERO_TOL) ? wv : 0.0f;

        // Order-preserving uint32 map of float order (no NaNs here).
        int   bits = __float_as_int(mxv);
        uint32_t ob = (uint32_t)(bits ^ ((bits >> 31) | 0x80000000));
        // 64-bit stable key: value major, (63-lane) minor -> all keys distinct,
        // strict > reproduces stable descending sort (earlier index first).
        uint64_t myk = ((uint64_t)ob << 32) | inv_lane;

        // 1) rank = number of strictly-greater keys. Broadcast key's low word
        //    is a compile-time constant -> ~3 VALU per iteration.
        int rank = 0;
        #pragma unroll
        for (int dp = 0; dp < 54; ++dp) {
            uint32_t obp = (uint32_t)__builtin_amdgcn_readlane((int)ob, dp);
            uint64_t kp  = ((uint64_t)obp << 32) | (uint32_t)(63 - dp);
            rank += (kp > myk) ? 1 : 0;
        }

        // 2) push weight and value into sorted coordinates (rank is a
        //    permutation of 0..63: idle lanes rank 54..63).
        int addr = rank << 2;
        float ws_r = __int_as_float(__builtin_amdgcn_ds_permute(addr, __float_as_int(wsel)));
        float mx_r = __int_as_float(__builtin_amdgcn_ds_permute(addr, __float_as_int(mxv)));

        // 3) sequential scan in sorted order — bit-exact np.cumsum association.
        float acc = 0.0f, cacc = 0.0f;
        #pragma unroll
        for (int r = 0; r < 54; ++r) {
            float wr = __int_as_float(__builtin_amdgcn_readlane(__float_as_int(ws_r), r));
            acc += wr;
            cacc = (lane == r) ? acc : cacc;
        }

        // 4) wave-uniform selection via masks (acc non-decreasing over nz
        //    positions => last nz with acc<=bias == reference's li-th nonzero;
        //    fallback = first nz position).
        const float bv = bias[nc];
        uint64_t nzm = __ballot(ws_r > 0.0f);
        uint64_t fm  = __ballot(cacc <= bv) & nzm;
        int rstar = fm ? (63 - __builtin_clzll(fm)) : __builtin_ctzll(nzm);
        float ans = __int_as_float(
            __builtin_amdgcn_readlane(__float_as_int(mx_r), rstar));
        res = (lane == nc) ? ans : res;
    }

    if (lane < 16) out[p * 16 + lane] = res;
}

extern "C" void kernel_launch(void* const* d_in, const int* in_sizes, int n_in,
                              void* d_out, int out_size, void* d_ws, size_t ws_size,
                              hipStream_t stream) {
    const float* x      = (const float*)d_in[0];
    const float* mask   = (const float*)d_in[1];
    const float* weight = (const float*)d_in[2];
    const float* bias   = (const float*)d_in[3];
    float* out = (float*)d_out;

    // 32768 pixels, 4 waves (pixels) per 256-thread block -> 8192 blocks
    wos_kernel<<<dim3(8192), dim3(256), 0, stream>>>(x, mask, weight, bias, out);
}

// Round 5
// 275.358 us; speedup vs baseline: 1.8349x; 1.8028x over previous
//
#include <hip/hip_runtime.h>
#include <limits.h>
#include <math.h>
#include <stdint.h>

#define WOS_ZERO_TOL 1e-6f
#define STRIDE 57   // 57 % 32 = 25 (odd) -> 16 channel rows hit 16 distinct banks

// One wave (64 lanes) per pixel.
// Phase 1 (per nc, wave-wide over candidates): lane d owns candidate d
//   (d<27: patch value, d>=27: negated); stable descending rank via u64 key
//   compare (verified bit-exact in rounds 2/4); scatter weight & value into
//   sorted LDS columns s_ws/s_mx[wid][nc][rank]  (rank 0..53 distinct,
//   <=2-way bank alias = free on CDNA4).
// Phase 2 (transposed): lane handles channel nc = lane&15; one 54-step
//   sequential scan advances ALL 16 channels at once. acc association order
//   identical to np.cumsum (adds exact zeros at sub-tol positions).
//   rstar = last r with (w!=0 && acc<=bias)  [acc monotone over nz => matches
//   reference li], fallback first-nz (clamped). Answer = s_mx[nc][rstar].
__global__ __launch_bounds__(256) void wos_kernel(
    const float* __restrict__ x,       // (8,3,64,64)
    const float* __restrict__ mask,    // (16,54)
    const float* __restrict__ weight,  // (16,54)
    const float* __restrict__ bias,    // (16,1)
    float* __restrict__ out)           // flat: [pixel*16 + nc]
{
    __shared__ float s_ws[4][16][STRIDE];
    __shared__ float s_mx[4][16][STRIDE];

    const int lane = threadIdx.x & 63;
    const int wid  = threadIdx.x >> 6;
    const int p    = blockIdx.x * 4 + wid;   // pixel in [0, 32768)
    const int b    = p >> 12;
    const int l    = p & 4095;
    const int h    = l >> 6;
    const int w    = l & 63;

    // Gather this lane's patch value (zero padding at borders).
    float inp = 0.0f;
    if (lane < 54) {
        int dm  = (lane < 27) ? lane : lane - 27;
        int c   = dm / 9;
        int rem = dm - 9 * c;
        int di  = rem / 3;
        int dj  = rem - 3 * di;
        int hh  = h + di - 1;
        int ww  = w + dj - 1;
        if (hh >= 0 && hh < 64 && ww >= 0 && ww < 64) {
            float v = x[((b * 3 + c) << 12) + (hh << 6) + ww];
            inp = (lane < 27) ? v : -v;
        }
    }

    const uint32_t inv_lane = (uint32_t)(63 - lane);

    // ---- Phase 1: rank + scatter into sorted coordinates ----
    #pragma unroll 1
    for (int nc = 0; nc < 16; ++nc) {
        float mk   = (lane < 54) ? mask[nc * 54 + lane]   : 0.0f;
        float wv   = (lane < 54) ? weight[nc * 54 + lane] : 0.0f;
        float mxv  = (lane < 54) ? (inp + mk) : -INFINITY;
        float wsel = (wv > WOS_ZERO_TOL) ? wv : 0.0f;

        // Order-preserving uint32 map of float order (no NaNs here).
        int      bits = __float_as_int(mxv);
        uint32_t ob   = (uint32_t)(bits ^ ((bits >> 31) | 0x80000000));
        // 64-bit stable key: value major, (63-lane) minor -> distinct keys,
        // strict > reproduces jnp's stable descending argsort exactly.
        uint64_t myk  = ((uint64_t)ob << 32) | inv_lane;

        int rank = 0;
        #pragma unroll
        for (int dp = 0; dp < 54; ++dp) {
            uint32_t obp = (uint32_t)__builtin_amdgcn_readlane((int)ob, dp);
            uint64_t kp  = ((uint64_t)obp << 32) | (uint32_t)(63 - dp);
            rank += (kp > myk) ? 1 : 0;
        }

        // Active lanes have ranks 0..53 (all beat the -inf idle keys).
        if (lane < 54) {
            s_ws[wid][nc][rank] = wsel;
            s_mx[wid][nc][rank] = mxv;
        }
    }
    // Same-wave LDS RAW: compiler inserts the lgkmcnt wait; no barrier needed
    // (each wave touches only its own [wid] slice).

    // ---- Phase 2: transposed sequential scan, lane = channel ----
    {
        const int   nc = lane & 15;       // lanes 16..63 run redundant copies
        const float bv = bias[nc];
        float acc   = 0.0f;
        int   rstar = -1;
        int   fnz   = 64;
        #pragma unroll
        for (int r = 0; r < 54; ++r) {
            float wr = s_ws[wid][nc][r];
            acc += wr;                                   // exact np.cumsum order
            bool nz = (__float_as_int(wr) != 0);
            rstar = (nz && acc <= bv) ? r : rstar;       // last nz with acc<=bias
            fnz   = (nz && r < fnz)   ? r : fnz;         // first nz (fallback)
        }
        if (rstar < 0) rstar = (fnz < 54) ? fnz : 0;     // unreachable in practice
        float ans = s_mx[wid][nc][rstar];
        if (lane < 16) out[p * 16 + lane] = ans;
    }
}

extern "C" void kernel_launch(void* const* d_in, const int* in_sizes, int n_in,
                              void* d_out, int out_size, void* d_ws, size_t ws_size,
                              hipStream_t stream) {
    const float* x      = (const float*)d_in[0];
    const float* mask   = (const float*)d_in[1];
    const float* weight = (const float*)d_in[2];
    const float* bias   = (const float*)d_in[3];
    float* out = (float*)d_out;

    // 32768 pixels, 4 waves (pixels) per 256-thread block -> 8192 blocks
    wos_kernel<<<dim3(8192), dim3(256), 0, stream>>>(x, mask, weight, bias, out);
}